// Round 10
// baseline (303.880 us; speedup 1.0000x reference)
//
#include <hip/hip_runtime.h>
#include <math.h>

#define BATCH 32
#define NPTS 1024
#define DIM 64
#define EPS_DIV 1e-8f
#define EPS_NORM 1e-8f
#define BN (BATCH * NPTS)
#define OFFQ ((size_t)BATCH * NPTS * DIM)

typedef __attribute__((ext_vector_type(8))) short short8v;
typedef __attribute__((ext_vector_type(4))) float f32x4;

static __device__ __forceinline__ unsigned short f2bf(float f) {
    unsigned u = __float_as_uint(f);
    return (unsigned short)((u + 0x7FFFu + ((u >> 16) & 1u)) >> 16);
}
static __device__ __forceinline__ float bf2f(unsigned short h) {
    return __uint_as_float(((unsigned)h) << 16);
}
static __device__ __forceinline__ float fsqrt(float x) {
#if __has_builtin(__builtin_amdgcn_sqrtf)
    return __builtin_amdgcn_sqrtf(x);
#else
    return sqrtf(x);
#endif
}

// 512 blocks x 256 threads (4 waves). launch_bounds(256,3): VGPR cap ~170,
// >=3 blocks/CU -> cooperative capacity 768 >= 512 (1.5x margin).
// Per-batch dataflow flags; phase A runs first in every block so all signals
// are posted before any spin (no circular wait).
__global__ __launch_bounds__(256, 3) void k_all(
    const float* __restrict__ p, const float* __restrict__ q,
    unsigned* __restrict__ flags,    // [0..31] readyA, [32..63] readyB, [64] done
    unsigned short* __restrict__ xb, float* __restrict__ rr,
    float* __restrict__ scpart, float* __restrict__ v,
    float* __restrict__ parts, float* __restrict__ out) {
    int t = threadIdx.x;
    int blk = blockIdx.x;
    int lane = t & 63, w = t >> 6;
    int lr = lane & 15, lk = lane >> 4;
    __shared__ float sm[256];
    __shared__ float svs[NPTS];
    __shared__ float cs[4][64];
    __shared__ float a1s[4][64], a2s[4][64];
    __shared__ unsigned lastflag;

    unsigned* readyA = flags;
    unsigned* readyB = flags + 32;
    unsigned* done   = flags + 64;

    // ============ phase A: prep (sel,b,chunk of 128 rows); 512 tasks ========
    {
        int sel = blk >> 8, rem = blk & 255;
        int b = rem >> 3, chunk = rem & 7;
        const float* src = (sel ? q : p) + ((size_t)b * NPTS + chunk * 128) * DIM;
        unsigned short* dst = xb + (sel ? OFFQ : 0)
                                 + ((size_t)b * NPTS + chunk * 128) * DIM;
        float* rrb = rr + sel * BN + b * NPTS + chunk * 128;
        float s = 0.f;
        #pragma unroll
        for (int it = 0; it < 8; it++) {
            int idx = it * 256 + t;              // float4 unit; 16 per row
            float4 vv = ((const float4*)src)[idx];
            s += vv.x + vv.y + vv.z + vv.w;
            unsigned short h0 = f2bf(vv.x), h1 = f2bf(vv.y),
                           h2 = f2bf(vv.z), h3 = f2bf(vv.w);
            float r0 = bf2f(h0), r1 = bf2f(h1), r2 = bf2f(h2), r3 = bf2f(h3);
            float ss = r0 * r0 + r1 * r1 + r2 * r2 + r3 * r3;
            ushort4 o; o.x = h0; o.y = h1; o.z = h2; o.w = h3;
            ((ushort4*)dst)[idx] = o;
            ss += __shfl_xor(ss, 1);
            ss += __shfl_xor(ss, 2);
            ss += __shfl_xor(ss, 4);
            ss += __shfl_xor(ss, 8);
            if ((t & 15) == 0) rrb[idx >> 4] = ss;
        }
        sm[t] = s;
        __syncthreads();
        for (int st = 128; st > 0; st >>= 1) {
            if (t < st) sm[t] += sm[t + st];
            __syncthreads();
        }
        if (t == 0) scpart[(sel * BATCH + b) * 8 + chunk] = sm[0];
        __threadfence();                          // release (all threads)
        __syncthreads();
        if (t == 0) atomicAdd(&readyA[b], 1u);    // target 16
    }

    // ============ phase B: colsum -> v (b, 64-col chunk); 512 tasks =========
    {
        int b = blk >> 4, jc = blk & 15;
        int j0 = jc * 64;
        if (t == 0) {
            while (__hip_atomic_load(&readyA[b], __ATOMIC_ACQUIRE,
                                     __HIP_MEMORY_SCOPE_AGENT) < 16u)
                __builtin_amdgcn_s_sleep(2);
            __threadfence();                      // acquire
        }
        __syncthreads();
        float sps = 0.f, sqs = 0.f;
        #pragma unroll
        for (int c = 0; c < 8; c++) {
            sps += scpart[b * 8 + c];
            sqs += scpart[(BATCH + b) * 8 + c];
        }
        float sp = 1.0f / (sps + EPS_NORM), sq = 1.0f / (sqs + EPS_NORM);
        float sp2 = sp * sp, sq2 = sq * sq, spq2 = 2.f * sp * sq;
        const unsigned short* xbase = xb + (size_t)b * NPTS * DIM;
        const unsigned short* ybase = xb + OFFQ + ((size_t)b * NPTS + j0) * DIM;
        const float* rrp = rr + b * NPTS;
        const float* rrq = rr + BN + b * NPTS;
        short8v bn[2][4];
        #pragma unroll
        for (int ks = 0; ks < 2; ks++)
            #pragma unroll
            for (int n = 0; n < 4; n++)
                bn[ks][n] = *(const short8v*)(ybase + (size_t)(n * 16 + lr) * DIM
                                              + ks * 32 + lk * 8);
        float yr[4];
        #pragma unroll
        for (int n = 0; n < 4; n++) yr[n] = sq2 * rrq[j0 + n * 16 + lr];
        float csn[4] = {0.f, 0.f, 0.f, 0.f};
        #pragma unroll
        for (int it = 0; it < 4; it++) {
            int ib = w * 256 + it * 64;           // wave's 64-row slab
            f32x4 acc[4][4];
            #pragma unroll
            for (int m = 0; m < 4; m++)
                #pragma unroll
                for (int n = 0; n < 4; n++) acc[m][n] = (f32x4){0.f, 0.f, 0.f, 0.f};
            #pragma unroll
            for (int ks = 0; ks < 2; ks++) {
                short8v am[4];
                #pragma unroll
                for (int m = 0; m < 4; m++)
                    am[m] = *(const short8v*)(xbase + (size_t)(ib + m * 16 + lr) * DIM
                                              + ks * 32 + lk * 8);
                #pragma unroll
                for (int m = 0; m < 4; m++)
                    #pragma unroll
                    for (int n = 0; n < 4; n++)
                        acc[m][n] = __builtin_amdgcn_mfma_f32_16x16x32_bf16(
                            am[m], bn[ks][n], acc[m][n], 0, 0, 0);
            }
            #pragma unroll
            for (int m = 0; m < 4; m++) {
                float4 xr = *(const float4*)(rrp + ib + m * 16 + lk * 4);
                float xs[4] = {xr.x * sp2, xr.y * sp2, xr.z * sp2, xr.w * sp2};
                #pragma unroll
                for (int n = 0; n < 4; n++)
                    #pragma unroll
                    for (int r = 0; r < 4; r++) {
                        float sqd = fmaxf(xs[r] + yr[n] - spq2 * acc[m][n][r], 0.f);
                        csn[n] += fsqrt(sqd);
                    }
            }
        }
        #pragma unroll
        for (int n = 0; n < 4; n++) {
            csn[n] += __shfl_xor(csn[n], 16);
            csn[n] += __shfl_xor(csn[n], 32);
        }
        if (lk == 0) {
            #pragma unroll
            for (int n = 0; n < 4; n++) cs[w][n * 16 + lr] = csn[n];
        }
        __syncthreads();
        if (t < 64) {
            float s = cs[0][t] + cs[1][t] + cs[2][t] + cs[3][t];
            float vj = 1.0f / (1.0f - s * (10.0f / NPTS) + EPS_DIV);
            v[b * NPTS + j0 + t] = vj;
        }
        __threadfence();                          // release (all threads)
        __syncthreads();
        if (t == 0) atomicAdd(&readyB[b], 1u);    // target 16
    }

    // ============ phase C: loss rows -> parts (b, 64-row chunk) =============
    {
        int b = blk >> 4, ic = blk & 15;
        int i0 = ic * 64;
        if (t == 0) {
            while (__hip_atomic_load(&readyB[b], __ATOMIC_ACQUIRE,
                                     __HIP_MEMORY_SCOPE_AGENT) < 16u)
                __builtin_amdgcn_s_sleep(2);
            __threadfence();                      // acquire
        }
        __syncthreads();
        ((float4*)svs)[t] = ((const float4*)(v + (size_t)b * NPTS))[t];
        __syncthreads();
        float acc4 = 0.f;
        #pragma unroll
        for (int k = 0; k < 4; k++) acc4 += svs[k * 256 + t];
        sm[t] = acc4;
        __syncthreads();
        for (int st = 128; st > 0; st >>= 1) {
            if (t < st) sm[t] += sm[t + st];
            __syncthreads();
        }
        float sV = sm[0];
        float sps = 0.f, sqs = 0.f;
        #pragma unroll
        for (int c = 0; c < 8; c++) {
            sps += scpart[b * 8 + c];
            sqs += scpart[(BATCH + b) * 8 + c];
        }
        float sp = 1.0f / (sps + EPS_NORM), sq = 1.0f / (sqs + EPS_NORM);
        float sp2 = sp * sp, sq2 = sq * sq, spq2 = 2.f * sp * sq;
        const unsigned short* xbase = xb + ((size_t)b * NPTS + i0) * DIM;
        const unsigned short* ybase = xb + OFFQ + (size_t)b * NPTS * DIM;
        const float* rrq = rr + BN + b * NPTS;
        short8v am[2][4];
        #pragma unroll
        for (int ks = 0; ks < 2; ks++)
            #pragma unroll
            for (int m = 0; m < 4; m++)
                am[ks][m] = *(const short8v*)(xbase + (size_t)(m * 16 + lr) * DIM
                                              + ks * 32 + lk * 8);
        float xs[4][4];
        #pragma unroll
        for (int m = 0; m < 4; m++) {
            float4 xr = *(const float4*)(rr + b * NPTS + i0 + m * 16 + lk * 4);
            xs[m][0] = xr.x * sp2; xs[m][1] = xr.y * sp2;
            xs[m][2] = xr.z * sp2; xs[m][3] = xr.w * sp2;
        }
        float a1[4][4] = {}, a2[4][4] = {};
        #pragma unroll
        for (int it = 0; it < 4; it++) {
            int jb = w * 256 + it * 64;           // wave's 64-col slab
            #pragma unroll
            for (int nh = 0; nh < 2; nh++) {      // n-split: acc[4][2] at a time
                f32x4 acc[4][2];
                #pragma unroll
                for (int m = 0; m < 4; m++)
                    #pragma unroll
                    for (int n = 0; n < 2; n++) acc[m][n] = (f32x4){0.f, 0.f, 0.f, 0.f};
                #pragma unroll
                for (int ks = 0; ks < 2; ks++) {
                    short8v bnf[2];
                    #pragma unroll
                    for (int n = 0; n < 2; n++)
                        bnf[n] = *(const short8v*)(ybase
                            + (size_t)(jb + (nh * 2 + n) * 16 + lr) * DIM
                            + ks * 32 + lk * 8);
                    #pragma unroll
                    for (int m = 0; m < 4; m++)
                        #pragma unroll
                        for (int n = 0; n < 2; n++)
                            acc[m][n] = __builtin_amdgcn_mfma_f32_16x16x32_bf16(
                                am[ks][m], bnf[n], acc[m][n], 0, 0, 0);
                }
                #pragma unroll
                for (int n = 0; n < 2; n++) {
                    int col = jb + (nh * 2 + n) * 16 + lr;
                    float yr = sq2 * rrq[col];
                    float vj = svs[col];
                    #pragma unroll
                    for (int m = 0; m < 4; m++)
                        #pragma unroll
                        for (int r = 0; r < 4; r++) {
                            float sqd = fmaxf(xs[m][r] + yr - spq2 * acc[m][n][r], 0.f);
                            float rt = fsqrt(sqd);
                            float tv = rt * vj;
                            a1[m][r] += tv;
                            float g = fmaf(-10.0f, rt, 1.0f);
                            a2[m][r] = fmaf(tv, g, a2[m][r]);
                        }
                }
            }
        }
        #pragma unroll
        for (int m = 0; m < 4; m++)
            #pragma unroll
            for (int r = 0; r < 4; r++) {
                #pragma unroll
                for (int st = 1; st < 16; st <<= 1) {
                    a1[m][r] += __shfl_xor(a1[m][r], st);
                    a2[m][r] += __shfl_xor(a2[m][r], st);
                }
            }
        if (lr == 0) {
            #pragma unroll
            for (int m = 0; m < 4; m++)
                #pragma unroll
                for (int r = 0; r < 4; r++) {
                    a1s[w][m * 16 + lk * 4 + r] = a1[m][r];
                    a2s[w][m * 16 + lk * 4 + r] = a2[m][r];
                }
        }
        __syncthreads();
        {
            float lp = 0.f;
            if (t < 64) {
                float A1 = a1s[0][t] + a1s[1][t] + a1s[2][t] + a1s[3][t];
                float A2 = a2s[0][t] + a2s[1][t] + a2s[2][t] + a2s[3][t];
                float u = 1.0f / (sV - 10.0f * A1 + EPS_DIV);
                lp = u * A2;
            }
            if (w == 0) {
                #pragma unroll
                for (int st = 1; st < 64; st <<= 1) lp += __shfl_xor(lp, st);
                if (t == 0) parts[b * 16 + ic] = lp;
            }
        }
    }

    // ============ last block: final reduce ==================================
    if (t == 0) {
        __threadfence();
        unsigned old = atomicAdd(done, 1u);
        lastflag = (old == 511u) ? 1u : 0u;
    }
    __syncthreads();
    if (lastflag) {
        __threadfence();                          // acquire: parts visible
        float a = parts[t] + parts[t + 256];
        sm[t] = a;
        __syncthreads();
        for (int st = 128; st > 0; st >>= 1) {
            if (t < st) sm[t] += sm[t + st];
            __syncthreads();
        }
        if (t == 0) out[0] = sm[0] / (float)BATCH;
    }
}

extern "C" void kernel_launch(void* const* d_in, const int* in_sizes, int n_in,
                              void* d_out, int out_size, void* d_ws, size_t ws_size,
                              hipStream_t stream) {
    const float* pred   = (const float*)d_in[0];
    const float* target = (const float*)d_in[1];
    float* out = (float*)d_out;

    unsigned* flags = (unsigned*)d_ws;                            // 65 ints used
    unsigned short* xb = (unsigned short*)((char*)d_ws + 4096);   // 8 MB bf16
    float* fs = (float*)(xb + 2 * OFFQ);
    float* rr     = fs;                                           // 2*BN
    float* v      = rr + 2 * BN;                                  // BN
    float* scpart = v + BN;                                       // 512
    float* parts  = scpart + 512;                                 // 512

    // Zero the WHOLE flag page (512 B) — round 9 zeroed only 256 B and left
    // done=flags[64] (bytes 256..259) poisoned -> final reduce never ran.
    hipMemsetAsync(flags, 0, 512, stream);

    void* args[] = {(void*)&pred, (void*)&target, (void*)&flags, (void*)&xb,
                    (void*)&rr, (void*)&scpart, (void*)&v, (void*)&parts,
                    (void*)&out};
    hipError_t e = hipLaunchCooperativeKernel((const void*)k_all, dim3(512),
                                              dim3(256), args, 0, stream);
    if (e != hipSuccess) {
        // 512 blocks at >=3 blocks/CU capacity are co-resident under a normal
        // launch too; the flag protocol stays deadlock-free.
        hipLaunchKernelGGL(k_all, dim3(512), dim3(256), 0, stream,
                           pred, target, flags, xb, rr, scpart, v, parts, out);
    }
}

// Round 11
// 119.945 us; speedup vs baseline: 2.5335x; 2.5335x over previous
//
#include <hip/hip_runtime.h>
#include <math.h>

#define BATCH 32
#define NPTS 1024
#define DIM 64
#define EPS_DIV 1e-8f
#define EPS_NORM 1e-8f
#define BN (BATCH * NPTS)
#define OFFQ ((size_t)BATCH * NPTS * DIM)

typedef __attribute__((ext_vector_type(8))) short short8v;
typedef __attribute__((ext_vector_type(4))) float f32x4;

static __device__ __forceinline__ unsigned short f2bf(float f) {
    unsigned u = __float_as_uint(f);
    return (unsigned short)((u + 0x7FFFu + ((u >> 16) & 1u)) >> 16);
}
static __device__ __forceinline__ float bf2f(unsigned short h) {
    return __uint_as_float(((unsigned)h) << 16);
}
static __device__ __forceinline__ float fsqrt(float x) {
#if __has_builtin(__builtin_amdgcn_sqrtf)
    return __builtin_amdgcn_sqrtf(x);
#else
    return sqrtf(x);
#endif
}

// ---- prep: 64-row chunks, fully coalesced; grid (16,2,BATCH) x 256 ----
__global__ __launch_bounds__(256) void k_prep(const float* __restrict__ p,
                                              const float* __restrict__ q,
                                              unsigned short* __restrict__ xb,
                                              float* __restrict__ rr,
                                              float* __restrict__ scpart) {
    int b = blockIdx.z, sel = blockIdx.y, chunk = blockIdx.x;
    const float* src = (sel ? q : p) + ((size_t)b * NPTS + chunk * 64) * DIM;
    unsigned short* dst = xb + (sel ? OFFQ : 0)
                             + ((size_t)b * NPTS + chunk * 64) * DIM;
    float* rrb = rr + sel * BN + b * NPTS + chunk * 64;
    int t = threadIdx.x;
    float s = 0.f;
    #pragma unroll
    for (int it = 0; it < 4; it++) {
        int idx = it * 256 + t;              // float4 unit; 16 per row
        float4 v = ((const float4*)src)[idx];
        s += v.x + v.y + v.z + v.w;
        unsigned short h0 = f2bf(v.x), h1 = f2bf(v.y), h2 = f2bf(v.z), h3 = f2bf(v.w);
        float r0 = bf2f(h0), r1 = bf2f(h1), r2 = bf2f(h2), r3 = bf2f(h3);
        float ss = r0 * r0 + r1 * r1 + r2 * r2 + r3 * r3;
        ushort4 o; o.x = h0; o.y = h1; o.z = h2; o.w = h3;
        ((ushort4*)dst)[idx] = o;
        ss += __shfl_xor(ss, 1);
        ss += __shfl_xor(ss, 2);
        ss += __shfl_xor(ss, 4);
        ss += __shfl_xor(ss, 8);
        if ((t & 15) == 0) rrb[it * 16 + (t >> 4)] = ss;
    }
    __shared__ float sm[256];
    sm[t] = s;
    __syncthreads();
    for (int st = 128; st > 0; st >>= 1) {
        if (t < st) sm[t] += sm[t + st];
        __syncthreads();
    }
    if (t == 0) scpart[(sel * BATCH + b) * 16 + chunk] = sm[0];
}

// ---- pass A: block owns 32 cols x ALL rows -> v; grid (32,BATCH) x 256 ----
__global__ __launch_bounds__(256) void k_colsum(const unsigned short* __restrict__ xb,
                                                const float* __restrict__ rr,
                                                const float* __restrict__ scpart,
                                                float* __restrict__ v) {
    int b = blockIdx.y, j0 = blockIdx.x * 32;
    int t = threadIdx.x, lane = t & 63, w = t >> 6;
    int lr = lane & 15, lk = lane >> 4;
    float sps = 0.f, sqs = 0.f;
    #pragma unroll
    for (int c = 0; c < 16; c++) {
        sps += scpart[b * 16 + c];
        sqs += scpart[(BATCH + b) * 16 + c];
    }
    float sp = 1.0f / (sps + EPS_NORM), sq = 1.0f / (sqs + EPS_NORM);
    float sp2 = sp * sp, sq2 = sq * sq, spq2 = 2.f * sp * sq;
    const unsigned short* xbase = xb + (size_t)b * NPTS * DIM;
    const unsigned short* ybase = xb + OFFQ + ((size_t)b * NPTS + j0) * DIM;
    const float* rrp = rr + b * NPTS;
    const float* rrq = rr + BN + b * NPTS;
    short8v bn[2][2];
    #pragma unroll
    for (int ks = 0; ks < 2; ks++)
        #pragma unroll
        for (int n = 0; n < 2; n++)
            bn[ks][n] = *(const short8v*)(ybase + (size_t)(n * 16 + lr) * DIM
                                          + ks * 32 + lk * 8);
    float yr[2];
    #pragma unroll
    for (int n = 0; n < 2; n++) yr[n] = sq2 * rrq[j0 + n * 16 + lr];
    float csn[2] = {0.f, 0.f};
    #pragma unroll
    for (int it = 0; it < 4; it++) {
        int ib = w * 256 + it * 64;              // wave's 64-row slab
        f32x4 acc[4][2];
        #pragma unroll
        for (int m = 0; m < 4; m++)
            #pragma unroll
            for (int n = 0; n < 2; n++) acc[m][n] = (f32x4){0.f, 0.f, 0.f, 0.f};
        #pragma unroll
        for (int ks = 0; ks < 2; ks++) {
            short8v am[4];
            #pragma unroll
            for (int m = 0; m < 4; m++)
                am[m] = *(const short8v*)(xbase + (size_t)(ib + m * 16 + lr) * DIM
                                          + ks * 32 + lk * 8);
            #pragma unroll
            for (int m = 0; m < 4; m++)
                #pragma unroll
                for (int n = 0; n < 2; n++)
                    acc[m][n] = __builtin_amdgcn_mfma_f32_16x16x32_bf16(
                        am[m], bn[ks][n], acc[m][n], 0, 0, 0);
        }
        #pragma unroll
        for (int m = 0; m < 4; m++) {
            float4 xr = *(const float4*)(rrp + ib + m * 16 + lk * 4);
            float xs[4] = {xr.x * sp2, xr.y * sp2, xr.z * sp2, xr.w * sp2};
            #pragma unroll
            for (int n = 0; n < 2; n++)
                #pragma unroll
                for (int r = 0; r < 4; r++) {
                    float sqd = fmaxf(xs[r] + yr[n] - spq2 * acc[m][n][r], 0.f);
                    csn[n] += fsqrt(sqd);
                }
        }
    }
    #pragma unroll
    for (int n = 0; n < 2; n++) {
        csn[n] += __shfl_xor(csn[n], 16);
        csn[n] += __shfl_xor(csn[n], 32);
    }
    __shared__ float cs[4][32];
    if (lk == 0) {
        #pragma unroll
        for (int n = 0; n < 2; n++) cs[w][n * 16 + lr] = csn[n];
    }
    __syncthreads();
    if (t < 32) {
        float s = cs[0][t] + cs[1][t] + cs[2][t] + cs[3][t];
        v[b * NPTS + j0 + t] = 1.0f / (1.0f - s * (10.0f / NPTS) + EPS_DIV);
    }
}

// ---- pass B: block owns 32 rows x ALL cols -> loss partial; last block
//      reduces all 1024 partials. grid (32,BATCH) x 256 ----
__global__ __launch_bounds__(256) void k_loss(const unsigned short* __restrict__ xb,
                                              const float* __restrict__ rr,
                                              const float* __restrict__ scpart,
                                              const float* __restrict__ v,
                                              float* __restrict__ parts,
                                              unsigned* __restrict__ done,
                                              float* __restrict__ out) {
    int b = blockIdx.y, i0 = blockIdx.x * 32;
    int t = threadIdx.x, lane = t & 63, w = t >> 6;
    int lr = lane & 15, lk = lane >> 4;
    __shared__ float svs[NPTS];
    __shared__ float syr[NPTS];
    __shared__ float sm[256];
    __shared__ unsigned lastflag;
    float sps = 0.f, sqs = 0.f;
    #pragma unroll
    for (int c = 0; c < 16; c++) {
        sps += scpart[b * 16 + c];
        sqs += scpart[(BATCH + b) * 16 + c];
    }
    float sp = 1.0f / (sps + EPS_NORM), sq = 1.0f / (sqs + EPS_NORM);
    float sp2 = sp * sp, sq2 = sq * sq, spq2 = 2.f * sp * sq;
    // stage v and sq2*rrq; compute sV
    {
        float4 vv = ((const float4*)(v + (size_t)b * NPTS))[t];
        ((float4*)svs)[t] = vv;
        float4 rq = ((const float4*)(rr + BN + (size_t)b * NPTS))[t];
        rq.x *= sq2; rq.y *= sq2; rq.z *= sq2; rq.w *= sq2;
        ((float4*)syr)[t] = rq;
        sm[t] = vv.x + vv.y + vv.z + vv.w;
    }
    __syncthreads();
    for (int st = 128; st > 0; st >>= 1) {
        if (t < st) sm[t] += sm[t + st];
        __syncthreads();
    }
    float sV = sm[0];
    const unsigned short* xbase = xb + ((size_t)b * NPTS + i0) * DIM;
    const unsigned short* ybase = xb + OFFQ + (size_t)b * NPTS * DIM;
    short8v am[2][2];
    #pragma unroll
    for (int ks = 0; ks < 2; ks++)
        #pragma unroll
        for (int m = 0; m < 2; m++)
            am[ks][m] = *(const short8v*)(xbase + (size_t)(m * 16 + lr) * DIM
                                          + ks * 32 + lk * 8);
    float xs[2][4];
    #pragma unroll
    for (int m = 0; m < 2; m++) {
        float4 xr = *(const float4*)(rr + b * NPTS + i0 + m * 16 + lk * 4);
        xs[m][0] = xr.x * sp2; xs[m][1] = xr.y * sp2;
        xs[m][2] = xr.z * sp2; xs[m][3] = xr.w * sp2;
    }
    float a1[2][4] = {}, a2[2][4] = {};
    #pragma unroll
    for (int it = 0; it < 4; it++) {
        int jb = w * 256 + it * 64;              // wave's 64-col slab
        f32x4 acc[2][4];
        #pragma unroll
        for (int m = 0; m < 2; m++)
            #pragma unroll
            for (int n = 0; n < 4; n++) acc[m][n] = (f32x4){0.f, 0.f, 0.f, 0.f};
        #pragma unroll
        for (int ks = 0; ks < 2; ks++) {
            short8v bnf[4];
            #pragma unroll
            for (int n = 0; n < 4; n++)
                bnf[n] = *(const short8v*)(ybase + (size_t)(jb + n * 16 + lr) * DIM
                                           + ks * 32 + lk * 8);
            #pragma unroll
            for (int m = 0; m < 2; m++)
                #pragma unroll
                for (int n = 0; n < 4; n++)
                    acc[m][n] = __builtin_amdgcn_mfma_f32_16x16x32_bf16(
                        am[ks][m], bnf[n], acc[m][n], 0, 0, 0);
        }
        #pragma unroll
        for (int n = 0; n < 4; n++) {
            int col = jb + n * 16 + lr;
            float yr = syr[col];
            float vj = svs[col];
            #pragma unroll
            for (int m = 0; m < 2; m++)
                #pragma unroll
                for (int r = 0; r < 4; r++) {
                    float sqd = fmaxf(xs[m][r] + yr - spq2 * acc[m][n][r], 0.f);
                    float rt = fsqrt(sqd);
                    float tv = rt * vj;
                    a1[m][r] += tv;
                    float g = fmaf(-10.0f, rt, 1.0f);
                    a2[m][r] = fmaf(tv, g, a2[m][r]);
                }
        }
    }
    #pragma unroll
    for (int m = 0; m < 2; m++)
        #pragma unroll
        for (int r = 0; r < 4; r++) {
            #pragma unroll
            for (int st = 1; st < 16; st <<= 1) {
                a1[m][r] += __shfl_xor(a1[m][r], st);
                a2[m][r] += __shfl_xor(a2[m][r], st);
            }
        }
    __shared__ float a1s[4][32], a2s[4][32];
    if (lr == 0) {
        #pragma unroll
        for (int m = 0; m < 2; m++)
            #pragma unroll
            for (int r = 0; r < 4; r++) {
                a1s[w][m * 16 + lk * 4 + r] = a1[m][r];
                a2s[w][m * 16 + lk * 4 + r] = a2[m][r];
            }
    }
    __syncthreads();
    {
        float lp = 0.f;
        if (t < 32) {
            float A1 = a1s[0][t] + a1s[1][t] + a1s[2][t] + a1s[3][t];
            float A2 = a2s[0][t] + a2s[1][t] + a2s[2][t] + a2s[3][t];
            float u = 1.0f / (sV - 10.0f * A1 + EPS_DIV);
            lp = u * A2;
        }
        if (w == 0) {
            #pragma unroll
            for (int st = 1; st < 32; st <<= 1) lp += __shfl_xor(lp, st);
            if (t == 0) parts[b * 32 + blockIdx.x] = lp;
        }
    }
    // last-block final reduce
    __threadfence();
    __syncthreads();
    if (t == 0) {
        unsigned old = atomicAdd(done, 1u);
        lastflag = (old == (unsigned)(BATCH * 32 - 1)) ? 1u : 0u;
    }
    __syncthreads();
    if (lastflag) {
        __threadfence();                          // acquire: parts visible
        float a = parts[t] + parts[t + 256] + parts[t + 512] + parts[t + 768];
        sm[t] = a;
        __syncthreads();
        for (int st = 128; st > 0; st >>= 1) {
            if (t < st) sm[t] += sm[t + st];
            __syncthreads();
        }
        if (t == 0) out[0] = sm[0] / (float)BATCH;
    }
}

extern "C" void kernel_launch(void* const* d_in, const int* in_sizes, int n_in,
                              void* d_out, int out_size, void* d_ws, size_t ws_size,
                              hipStream_t stream) {
    const float* pred   = (const float*)d_in[0];
    const float* target = (const float*)d_in[1];
    float* out = (float*)d_out;

    unsigned* flags = (unsigned*)d_ws;                            // done counter
    unsigned short* xb = (unsigned short*)((char*)d_ws + 4096);   // 8 MB bf16
    float* fs = (float*)(xb + 2 * OFFQ);
    float* rr     = fs;                                           // 2*BN
    float* v      = rr + 2 * BN;                                  // BN
    float* scpart = v + BN;                                       // 1024
    float* parts  = scpart + 1024;                                // 1024

    hipMemsetAsync(flags, 0, 512, stream);
    k_prep<<<dim3(16, 2, BATCH), 256, 0, stream>>>(pred, target, xb, rr, scpart);
    k_colsum<<<dim3(32, BATCH), 256, 0, stream>>>(xb, rr, scpart, v);
    k_loss<<<dim3(32, BATCH), 256, 0, stream>>>(xb, rr, scpart, v, parts, flags, out);
}

// Round 12
// 69.288 us; speedup vs baseline: 4.3858x; 1.7311x over previous
//
#include <hip/hip_runtime.h>
#include <math.h>

#define BATCH 32
#define NPTS 1024
#define DIM 64
#define EPS_DIV 1e-8f
#define EPS_NORM 1e-8f
#define BN (BATCH * NPTS)
#define OFFQ ((size_t)BATCH * NPTS * DIM)

typedef __attribute__((ext_vector_type(8))) short short8v;
typedef __attribute__((ext_vector_type(4))) float f32x4;

static __device__ __forceinline__ unsigned short f2bf(float f) {
    unsigned u = __float_as_uint(f);
    return (unsigned short)((u + 0x7FFFu + ((u >> 16) & 1u)) >> 16);
}
static __device__ __forceinline__ float bf2f(unsigned short h) {
    return __uint_as_float(((unsigned)h) << 16);
}
static __device__ __forceinline__ float fsqrt(float x) {
#if __has_builtin(__builtin_amdgcn_sqrtf)
    return __builtin_amdgcn_sqrtf(x);
#else
    return sqrtf(x);
#endif
}

// ---- prep: 64-row chunks, fully coalesced; grid (16,2,BATCH) x 256 ----
__global__ __launch_bounds__(256) void k_prep(const float* __restrict__ p,
                                              const float* __restrict__ q,
                                              unsigned short* __restrict__ xb,
                                              float* __restrict__ rr,
                                              float* __restrict__ scpart) {
    int b = blockIdx.z, sel = blockIdx.y, chunk = blockIdx.x;
    const float* src = (sel ? q : p) + ((size_t)b * NPTS + chunk * 64) * DIM;
    unsigned short* dst = xb + (sel ? OFFQ : 0)
                             + ((size_t)b * NPTS + chunk * 64) * DIM;
    float* rrb = rr + sel * BN + b * NPTS + chunk * 64;
    int t = threadIdx.x;
    float s = 0.f;
    #pragma unroll
    for (int it = 0; it < 4; it++) {
        int idx = it * 256 + t;              // float4 unit; 16 per row
        float4 v = ((const float4*)src)[idx];
        s += v.x + v.y + v.z + v.w;
        unsigned short h0 = f2bf(v.x), h1 = f2bf(v.y), h2 = f2bf(v.z), h3 = f2bf(v.w);
        float r0 = bf2f(h0), r1 = bf2f(h1), r2 = bf2f(h2), r3 = bf2f(h3);
        float ss = r0 * r0 + r1 * r1 + r2 * r2 + r3 * r3;
        ushort4 o; o.x = h0; o.y = h1; o.z = h2; o.w = h3;
        ((ushort4*)dst)[idx] = o;
        ss += __shfl_xor(ss, 1);
        ss += __shfl_xor(ss, 2);
        ss += __shfl_xor(ss, 4);
        ss += __shfl_xor(ss, 8);
        if ((t & 15) == 0) rrb[it * 16 + (t >> 4)] = ss;
    }
    __shared__ float sm[256];
    sm[t] = s;
    __syncthreads();
    for (int st = 128; st > 0; st >>= 1) {
        if (t < st) sm[t] += sm[t + st];
        __syncthreads();
    }
    if (t == 0) scpart[(sel * BATCH + b) * 16 + chunk] = sm[0];
}

// ---- pass A: block owns 32 cols x ALL rows -> v; grid (32,BATCH) x 256 ----
__global__ __launch_bounds__(256) void k_colsum(const unsigned short* __restrict__ xb,
                                                const float* __restrict__ rr,
                                                const float* __restrict__ scpart,
                                                float* __restrict__ v) {
    int b = blockIdx.y, j0 = blockIdx.x * 32;
    int t = threadIdx.x, lane = t & 63, w = t >> 6;
    int lr = lane & 15, lk = lane >> 4;
    float sps = 0.f, sqs = 0.f;
    #pragma unroll
    for (int c = 0; c < 16; c++) {
        sps += scpart[b * 16 + c];
        sqs += scpart[(BATCH + b) * 16 + c];
    }
    float sp = 1.0f / (sps + EPS_NORM), sq = 1.0f / (sqs + EPS_NORM);
    float sp2 = sp * sp, sq2 = sq * sq, spq2 = 2.f * sp * sq;
    const unsigned short* xbase = xb + (size_t)b * NPTS * DIM;
    const unsigned short* ybase = xb + OFFQ + ((size_t)b * NPTS + j0) * DIM;
    const float* rrp = rr + b * NPTS;
    const float* rrq = rr + BN + b * NPTS;
    short8v bn[2][2];
    #pragma unroll
    for (int ks = 0; ks < 2; ks++)
        #pragma unroll
        for (int n = 0; n < 2; n++)
            bn[ks][n] = *(const short8v*)(ybase + (size_t)(n * 16 + lr) * DIM
                                          + ks * 32 + lk * 8);
    float yr[2];
    #pragma unroll
    for (int n = 0; n < 2; n++) yr[n] = sq2 * rrq[j0 + n * 16 + lr];
    float csn[2] = {0.f, 0.f};
    #pragma unroll
    for (int it = 0; it < 4; it++) {
        int ib = w * 256 + it * 64;              // wave's 64-row slab
        f32x4 acc[4][2];
        #pragma unroll
        for (int m = 0; m < 4; m++)
            #pragma unroll
            for (int n = 0; n < 2; n++) acc[m][n] = (f32x4){0.f, 0.f, 0.f, 0.f};
        #pragma unroll
        for (int ks = 0; ks < 2; ks++) {
            short8v am[4];
            #pragma unroll
            for (int m = 0; m < 4; m++)
                am[m] = *(const short8v*)(xbase + (size_t)(ib + m * 16 + lr) * DIM
                                          + ks * 32 + lk * 8);
            #pragma unroll
            for (int m = 0; m < 4; m++)
                #pragma unroll
                for (int n = 0; n < 2; n++)
                    acc[m][n] = __builtin_amdgcn_mfma_f32_16x16x32_bf16(
                        am[m], bn[ks][n], acc[m][n], 0, 0, 0);
        }
        #pragma unroll
        for (int m = 0; m < 4; m++) {
            float4 xr = *(const float4*)(rrp + ib + m * 16 + lk * 4);
            float xs[4] = {xr.x * sp2, xr.y * sp2, xr.z * sp2, xr.w * sp2};
            #pragma unroll
            for (int n = 0; n < 2; n++)
                #pragma unroll
                for (int r = 0; r < 4; r++) {
                    float sqd = fmaxf(xs[r] + yr[n] - spq2 * acc[m][n][r], 0.f);
                    csn[n] += fsqrt(sqd);
                }
        }
    }
    #pragma unroll
    for (int n = 0; n < 2; n++) {
        csn[n] += __shfl_xor(csn[n], 16);
        csn[n] += __shfl_xor(csn[n], 32);
    }
    __shared__ float cs[4][32];
    if (lk == 0) {
        #pragma unroll
        for (int n = 0; n < 2; n++) cs[w][n * 16 + lr] = csn[n];
    }
    __syncthreads();
    if (t < 32) {
        float s = cs[0][t] + cs[1][t] + cs[2][t] + cs[3][t];
        v[b * NPTS + j0 + t] = 1.0f / (1.0f - s * (10.0f / NPTS) + EPS_DIV);
    }
}

// ---- pass B: block owns 32 rows x ALL cols -> loss partial; grid (32,BATCH) x 256 ----
__global__ __launch_bounds__(256) void k_loss(const unsigned short* __restrict__ xb,
                                              const float* __restrict__ rr,
                                              const float* __restrict__ scpart,
                                              const float* __restrict__ v,
                                              float* __restrict__ parts) {
    int b = blockIdx.y, i0 = blockIdx.x * 32;
    int t = threadIdx.x, lane = t & 63, w = t >> 6;
    int lr = lane & 15, lk = lane >> 4;
    __shared__ float svs[NPTS];
    __shared__ float syr[NPTS];
    __shared__ float sm[256];
    float sps = 0.f, sqs = 0.f;
    #pragma unroll
    for (int c = 0; c < 16; c++) {
        sps += scpart[b * 16 + c];
        sqs += scpart[(BATCH + b) * 16 + c];
    }
    float sp = 1.0f / (sps + EPS_NORM), sq = 1.0f / (sqs + EPS_NORM);
    float sp2 = sp * sp, sq2 = sq * sq, spq2 = 2.f * sp * sq;
    // stage v and sq2*rrq; compute sV
    {
        float4 vv = ((const float4*)(v + (size_t)b * NPTS))[t];
        ((float4*)svs)[t] = vv;
        float4 rq = ((const float4*)(rr + BN + (size_t)b * NPTS))[t];
        rq.x *= sq2; rq.y *= sq2; rq.z *= sq2; rq.w *= sq2;
        ((float4*)syr)[t] = rq;
        sm[t] = vv.x + vv.y + vv.z + vv.w;
    }
    __syncthreads();
    for (int st = 128; st > 0; st >>= 1) {
        if (t < st) sm[t] += sm[t + st];
        __syncthreads();
    }
    float sV = sm[0];
    const unsigned short* xbase = xb + ((size_t)b * NPTS + i0) * DIM;
    const unsigned short* ybase = xb + OFFQ + (size_t)b * NPTS * DIM;
    short8v am[2][2];
    #pragma unroll
    for (int ks = 0; ks < 2; ks++)
        #pragma unroll
        for (int m = 0; m < 2; m++)
            am[ks][m] = *(const short8v*)(xbase + (size_t)(m * 16 + lr) * DIM
                                          + ks * 32 + lk * 8);
    float xs[2][4];
    #pragma unroll
    for (int m = 0; m < 2; m++) {
        float4 xr = *(const float4*)(rr + b * NPTS + i0 + m * 16 + lk * 4);
        xs[m][0] = xr.x * sp2; xs[m][1] = xr.y * sp2;
        xs[m][2] = xr.z * sp2; xs[m][3] = xr.w * sp2;
    }
    float a1[2][4] = {}, a2[2][4] = {};
    #pragma unroll
    for (int it = 0; it < 4; it++) {
        int jb = w * 256 + it * 64;              // wave's 64-col slab
        f32x4 acc[2][4];
        #pragma unroll
        for (int m = 0; m < 2; m++)
            #pragma unroll
            for (int n = 0; n < 4; n++) acc[m][n] = (f32x4){0.f, 0.f, 0.f, 0.f};
        #pragma unroll
        for (int ks = 0; ks < 2; ks++) {
            short8v bnf[4];
            #pragma unroll
            for (int n = 0; n < 4; n++)
                bnf[n] = *(const short8v*)(ybase + (size_t)(jb + n * 16 + lr) * DIM
                                           + ks * 32 + lk * 8);
            #pragma unroll
            for (int m = 0; m < 2; m++)
                #pragma unroll
                for (int n = 0; n < 4; n++)
                    acc[m][n] = __builtin_amdgcn_mfma_f32_16x16x32_bf16(
                        am[ks][m], bnf[n], acc[m][n], 0, 0, 0);
        }
        #pragma unroll
        for (int n = 0; n < 4; n++) {
            int col = jb + n * 16 + lr;
            float yr = syr[col];
            float vj = svs[col];
            #pragma unroll
            for (int m = 0; m < 2; m++)
                #pragma unroll
                for (int r = 0; r < 4; r++) {
                    float sqd = fmaxf(xs[m][r] + yr - spq2 * acc[m][n][r], 0.f);
                    float rt = fsqrt(sqd);
                    float tv = rt * vj;
                    a1[m][r] += tv;
                    float g = fmaf(-10.0f, rt, 1.0f);
                    a2[m][r] = fmaf(tv, g, a2[m][r]);
                }
        }
    }
    #pragma unroll
    for (int m = 0; m < 2; m++)
        #pragma unroll
        for (int r = 0; r < 4; r++) {
            #pragma unroll
            for (int st = 1; st < 16; st <<= 1) {
                a1[m][r] += __shfl_xor(a1[m][r], st);
                a2[m][r] += __shfl_xor(a2[m][r], st);
            }
        }
    __shared__ float a1s[4][32], a2s[4][32];
    if (lr == 0) {
        #pragma unroll
        for (int m = 0; m < 2; m++)
            #pragma unroll
            for (int r = 0; r < 4; r++) {
                a1s[w][m * 16 + lk * 4 + r] = a1[m][r];
                a2s[w][m * 16 + lk * 4 + r] = a2[m][r];
            }
    }
    __syncthreads();
    {
        float lp = 0.f;
        if (t < 32) {
            float A1 = a1s[0][t] + a1s[1][t] + a1s[2][t] + a1s[3][t];
            float A2 = a2s[0][t] + a2s[1][t] + a2s[2][t] + a2s[3][t];
            float u = 1.0f / (sV - 10.0f * A1 + EPS_DIV);
            lp = u * A2;
        }
        if (w == 0) {
            #pragma unroll
            for (int st = 1; st < 32; st <<= 1) lp += __shfl_xor(lp, st);
            if (t == 0) parts[b * 32 + blockIdx.x] = lp;
        }
    }
}

// ---- final: one block reduces 1024 partials ----
__global__ void k_final(const float* __restrict__ parts, float* __restrict__ out) {
    __shared__ float sm[256];
    int t = threadIdx.x;
    float a = parts[t] + parts[t + 256] + parts[t + 512] + parts[t + 768];
    sm[t] = a;
    __syncthreads();
    for (int st = 128; st > 0; st >>= 1) {
        if (t < st) sm[t] += sm[t + st];
        __syncthreads();
    }
    if (t == 0) out[0] = sm[0] / (float)BATCH;
}

extern "C" void kernel_launch(void* const* d_in, const int* in_sizes, int n_in,
                              void* d_out, int out_size, void* d_ws, size_t ws_size,
                              hipStream_t stream) {
    const float* pred   = (const float*)d_in[0];
    const float* target = (const float*)d_in[1];
    float* out = (float*)d_out;

    unsigned short* xb = (unsigned short*)d_ws;                   // 8 MB bf16
    float* fs = (float*)(xb + 2 * OFFQ);
    float* rr     = fs;                                           // 2*BN
    float* v      = rr + 2 * BN;                                  // BN
    float* scpart = v + BN;                                       // 1024
    float* parts  = scpart + 1024;                                // 1024

    k_prep<<<dim3(16, 2, BATCH), 256, 0, stream>>>(pred, target, xb, rr, scpart);
    k_colsum<<<dim3(32, BATCH), 256, 0, stream>>>(xb, rr, scpart, v);
    k_loss<<<dim3(32, BATCH), 256, 0, stream>>>(xb, rr, scpart, v, parts);
    k_final<<<1, 256, 0, stream>>>(parts, out);
}

// Round 13
// 53.039 us; speedup vs baseline: 5.7294x; 1.3064x over previous
//
#include <hip/hip_runtime.h>
#include <math.h>

#define BATCH 32
#define NPTS 1024
#define DIM 64
#define EPS_DIV 1e-8f
#define EPS_NORM 1e-8f
#define BN (BATCH * NPTS)
#define OFFQ ((size_t)BATCH * NPTS * DIM)   // shorts per tensor
#define BSHORTS (NPTS * DIM)                // shorts per batch-matrix

typedef __attribute__((ext_vector_type(8))) short short8v;
typedef __attribute__((ext_vector_type(4))) float f32x4;

static __device__ __forceinline__ unsigned short f2bf(float f) {
    unsigned u = __float_as_uint(f);
    return (unsigned short)((u + 0x7FFFu + ((u >> 16) & 1u)) >> 16);
}
static __device__ __forceinline__ float bf2f(unsigned short h) {
    return __uint_as_float(((unsigned)h) << 16);
}
static __device__ __forceinline__ float fsqrt(float x) {
#if __has_builtin(__builtin_amdgcn_sqrtf)
    return __builtin_amdgcn_sqrtf(x);
#else
    return sqrtf(x);
#endif
}

// Fragment-major layout per batch-matrix: [64 rowgroups][8 cu][16 lr][8 bf16]
// shorts offset = rg*1024 + cu*128 + lr*8, cu = ks*4 + lk.
// A wave's MFMA fragment load (lanes (lr,lk), fixed rg,ks) = 1KB contiguous.

// ---- prep: 64-row chunks; cast + sums + LDS-transpose to fragment-major ----
__global__ __launch_bounds__(256) void k_prep(const float* __restrict__ p,
                                              const float* __restrict__ q,
                                              unsigned short* __restrict__ xb,
                                              float* __restrict__ rr,
                                              float* __restrict__ scpart) {
    int b = blockIdx.z, sel = blockIdx.y, chunk = blockIdx.x;
    const float* src = (sel ? q : p) + ((size_t)b * NPTS + chunk * 64) * DIM;
    unsigned short* dstb = xb + (sel ? OFFQ : 0) + (size_t)b * BSHORTS;
    float* rrb = rr + sel * BN + b * NPTS + chunk * 64;
    int t = threadIdx.x;
    __shared__ unsigned short lds[64][72];   // padded: 144B row stride
    __shared__ float sm[256];
    float s = 0.f;
    #pragma unroll
    for (int it = 0; it < 4; it++) {
        int idx = it * 256 + t;              // float4 unit; 16 per row
        int row = idx >> 4, dq = idx & 15;
        float4 v = ((const float4*)src)[idx];
        s += v.x + v.y + v.z + v.w;
        unsigned short h0 = f2bf(v.x), h1 = f2bf(v.y), h2 = f2bf(v.z), h3 = f2bf(v.w);
        float r0 = bf2f(h0), r1 = bf2f(h1), r2 = bf2f(h2), r3 = bf2f(h3);
        float ss = r0 * r0 + r1 * r1 + r2 * r2 + r3 * r3;
        ushort4 o; o.x = h0; o.y = h1; o.z = h2; o.w = h3;
        *(ushort4*)&lds[row][dq * 4] = o;
        ss += __shfl_xor(ss, 1);
        ss += __shfl_xor(ss, 2);
        ss += __shfl_xor(ss, 4);
        ss += __shfl_xor(ss, 8);
        if ((t & 15) == 0) rrb[it * 16 + (t >> 4)] = ss;
    }
    sm[t] = s;
    __syncthreads();
    // write fragment-major: 512 16-B units; unit u: rg=u>>7, cu=(u>>4)&7, lr=u&15
    #pragma unroll
    for (int o = 0; o < 2; o++) {
        int u = o * 256 + t;
        int rg = u >> 7, cu = (u >> 4) & 7, lr_ = u & 15;
        int row = rg * 16 + lr_;
        uint4 val = *(const uint4*)&lds[row][cu * 8];
        size_t dstS = (size_t)(chunk * 4 + rg) * 1024 + cu * 128 + lr_ * 8;
        *(uint4*)(dstb + dstS) = val;
    }
    for (int st = 128; st > 0; st >>= 1) {
        if (t < st) sm[t] += sm[t + st];
        __syncthreads();
    }
    if (t == 0) scpart[(sel * BATCH + b) * 16 + chunk] = sm[0];
}

// ---- pass A: block owns 64 cols x ALL rows -> v; grid (16,BATCH) x 512 ----
__global__ __launch_bounds__(512) void k_colsum(const unsigned short* __restrict__ xb,
                                                const float* __restrict__ rr,
                                                const float* __restrict__ scpart,
                                                float* __restrict__ v) {
    int b = blockIdx.y, j0 = blockIdx.x * 64;
    int t = threadIdx.x, lane = t & 63, w = t >> 6;
    int lr = lane & 15, lk = lane >> 4;
    float sps = 0.f, sqs = 0.f;
    #pragma unroll
    for (int c = 0; c < 16; c++) {
        sps += scpart[b * 16 + c];
        sqs += scpart[(BATCH + b) * 16 + c];
    }
    float sp = 1.0f / (sps + EPS_NORM), sq = 1.0f / (sqs + EPS_NORM);
    float sp2 = sp * sp, sq2 = sq * sq, spq2 = 2.f * sp * sq;
    const unsigned short* xbase = xb + (size_t)b * BSHORTS;
    const unsigned short* ybase = xb + OFFQ + (size_t)b * BSHORTS;
    const float* rrp = rr + b * NPTS;
    const float* rrq = rr + BN + b * NPTS;
    // hoisted B fragments + yr (fixed for the whole block)
    short8v bn[2][4];
    #pragma unroll
    for (int ks = 0; ks < 2; ks++)
        #pragma unroll
        for (int n = 0; n < 4; n++)
            bn[ks][n] = *(const short8v*)(ybase + (size_t)(blockIdx.x * 4 + n) * 1024
                                          + (ks * 4 + lk) * 128 + lr * 8);
    float yr[4];
    #pragma unroll
    for (int n = 0; n < 4; n++) yr[n] = sq2 * rrq[j0 + n * 16 + lr];
    float csn[4] = {0.f, 0.f, 0.f, 0.f};
    #pragma unroll
    for (int it = 0; it < 2; it++) {
        int ib = w * 128 + it * 64;
        int rg0 = w * 8 + it * 4;
        f32x4 acc[4][4];
        #pragma unroll
        for (int m = 0; m < 4; m++)
            #pragma unroll
            for (int n = 0; n < 4; n++) acc[m][n] = (f32x4){0.f, 0.f, 0.f, 0.f};
        #pragma unroll
        for (int ks = 0; ks < 2; ks++) {
            short8v am[4];
            #pragma unroll
            for (int m = 0; m < 4; m++)
                am[m] = *(const short8v*)(xbase + (size_t)(rg0 + m) * 1024
                                          + (ks * 4 + lk) * 128 + lr * 8);
            #pragma unroll
            for (int m = 0; m < 4; m++)
                #pragma unroll
                for (int n = 0; n < 4; n++)
                    acc[m][n] = __builtin_amdgcn_mfma_f32_16x16x32_bf16(
                        am[m], bn[ks][n], acc[m][n], 0, 0, 0);
        }
        #pragma unroll
        for (int m = 0; m < 4; m++) {
            float4 xr = *(const float4*)(rrp + ib + m * 16 + lk * 4);
            float xs[4] = {xr.x * sp2, xr.y * sp2, xr.z * sp2, xr.w * sp2};
            #pragma unroll
            for (int n = 0; n < 4; n++)
                #pragma unroll
                for (int r = 0; r < 4; r++) {
                    float sqd = fmaxf(xs[r] + yr[n] - spq2 * acc[m][n][r], 0.f);
                    csn[n] += fsqrt(sqd);
                }
        }
    }
    #pragma unroll
    for (int n = 0; n < 4; n++) {
        csn[n] += __shfl_xor(csn[n], 16);
        csn[n] += __shfl_xor(csn[n], 32);
    }
    __shared__ float cs[8][64];
    if (lk == 0) {
        #pragma unroll
        for (int n = 0; n < 4; n++) cs[w][n * 16 + lr] = csn[n];
    }
    __syncthreads();
    if (t < 64) {
        float s = 0.f;
        #pragma unroll
        for (int ww = 0; ww < 8; ww++) s += cs[ww][t];
        v[b * NPTS + j0 + t] = 1.0f / (1.0f - s * (10.0f / NPTS) + EPS_DIV);
    }
}

// ---- pass B: block owns 64 rows x ALL cols -> loss partial; grid (16,BATCH) x 512 ----
__global__ __launch_bounds__(512) void k_loss(const unsigned short* __restrict__ xb,
                                              const float* __restrict__ rr,
                                              const float* __restrict__ scpart,
                                              const float* __restrict__ v,
                                              float* __restrict__ parts) {
    int b = blockIdx.y, i0 = blockIdx.x * 64;
    int t = threadIdx.x, lane = t & 63, w = t >> 6;
    int lr = lane & 15, lk = lane >> 4;
    __shared__ float svs[NPTS];
    __shared__ float red[256];
    __shared__ float a1s[8][64], a2s[8][64];
    __shared__ float lsum[8];
    if (t < 256) ((float4*)svs)[t] = ((const float4*)(v + (size_t)b * NPTS))[t];
    float sps = 0.f, sqs = 0.f;
    #pragma unroll
    for (int c = 0; c < 16; c++) {
        sps += scpart[b * 16 + c];
        sqs += scpart[(BATCH + b) * 16 + c];
    }
    float sp = 1.0f / (sps + EPS_NORM), sq = 1.0f / (sqs + EPS_NORM);
    float sp2 = sp * sp, sq2 = sq * sq, spq2 = 2.f * sp * sq;
    __syncthreads();
    if (t < 256) red[t] = svs[t] + svs[t + 256] + svs[t + 512] + svs[t + 768];
    __syncthreads();
    for (int st = 128; st > 0; st >>= 1) {
        if (t < st && t < 256) red[t] += red[t + st];
        __syncthreads();
    }
    float sV = red[0];
    const unsigned short* xbase = xb + (size_t)b * BSHORTS;
    const unsigned short* ybase = xb + OFFQ + (size_t)b * BSHORTS;
    const float* rrq = rr + BN + b * NPTS;
    // hoisted A fragments + xr (fixed rows for the whole block)
    short8v am[2][4];
    #pragma unroll
    for (int ks = 0; ks < 2; ks++)
        #pragma unroll
        for (int m = 0; m < 4; m++)
            am[ks][m] = *(const short8v*)(xbase + (size_t)(blockIdx.x * 4 + m) * 1024
                                          + (ks * 4 + lk) * 128 + lr * 8);
    float xs[4][4];
    #pragma unroll
    for (int m = 0; m < 4; m++) {
        float4 xr = *(const float4*)(rr + b * NPTS + i0 + m * 16 + lk * 4);
        xs[m][0] = xr.x * sp2; xs[m][1] = xr.y * sp2;
        xs[m][2] = xr.z * sp2; xs[m][3] = xr.w * sp2;
    }
    float a1[4][4] = {}, a2[4][4] = {};
    #pragma unroll
    for (int it = 0; it < 2; it++) {
        int jb = w * 128 + it * 64;
        int rg0 = w * 8 + it * 4;
        f32x4 acc[4][4];
        #pragma unroll
        for (int m = 0; m < 4; m++)
            #pragma unroll
            for (int n = 0; n < 4; n++) acc[m][n] = (f32x4){0.f, 0.f, 0.f, 0.f};
        #pragma unroll
        for (int ks = 0; ks < 2; ks++) {
            short8v bnf[4];
            #pragma unroll
            for (int n = 0; n < 4; n++)
                bnf[n] = *(const short8v*)(ybase + (size_t)(rg0 + n) * 1024
                                           + (ks * 4 + lk) * 128 + lr * 8);
            #pragma unroll
            for (int m = 0; m < 4; m++)
                #pragma unroll
                for (int n = 0; n < 4; n++)
                    acc[m][n] = __builtin_amdgcn_mfma_f32_16x16x32_bf16(
                        am[ks][m], bnf[n], acc[m][n], 0, 0, 0);
        }
        #pragma unroll
        for (int n = 0; n < 4; n++) {
            int col = jb + n * 16 + lr;
            float yr = sq2 * rrq[col];
            float vj = svs[col];
            #pragma unroll
            for (int m = 0; m < 4; m++)
                #pragma unroll
                for (int r = 0; r < 4; r++) {
                    float sqd = fmaxf(xs[m][r] + yr - spq2 * acc[m][n][r], 0.f);
                    float rt = fsqrt(sqd);
                    float tv = rt * vj;
                    a1[m][r] += tv;
                    float g = fmaf(-10.0f, rt, 1.0f);
                    a2[m][r] = fmaf(tv, g, a2[m][r]);
                }
        }
    }
    #pragma unroll
    for (int m = 0; m < 4; m++)
        #pragma unroll
        for (int r = 0; r < 4; r++) {
            #pragma unroll
            for (int st = 1; st < 16; st <<= 1) {
                a1[m][r] += __shfl_xor(a1[m][r], st);
                a2[m][r] += __shfl_xor(a2[m][r], st);
            }
        }
    if (lr == 0) {
        #pragma unroll
        for (int m = 0; m < 4; m++)
            #pragma unroll
            for (int r = 0; r < 4; r++) {
                a1s[w][m * 16 + lk * 4 + r] = a1[m][r];
                a2s[w][m * 16 + lk * 4 + r] = a2[m][r];
            }
    }
    __syncthreads();
    if (t < 64) {
        float A1 = 0.f, A2 = 0.f;
        #pragma unroll
        for (int ww = 0; ww < 8; ww++) {
            A1 += a1s[ww][t];
            A2 += a2s[ww][t];
        }
        float u = 1.0f / (sV - 10.0f * A1 + EPS_DIV);
        float lp = u * A2;
        #pragma unroll
        for (int st = 1; st < 64; st <<= 1) lp += __shfl_xor(lp, st);
        if (t == 0) parts[b * 16 + blockIdx.x] = lp;
    }
}

// ---- final: one block reduces 512 partials ----
__global__ void k_final(const float* __restrict__ parts, float* __restrict__ out) {
    __shared__ float sm[256];
    int t = threadIdx.x;
    float a = parts[t] + parts[t + 256];
    sm[t] = a;
    __syncthreads();
    for (int st = 128; st > 0; st >>= 1) {
        if (t < st) sm[t] += sm[t + st];
        __syncthreads();
    }
    if (t == 0) out[0] = sm[0] / (float)BATCH;
}

extern "C" void kernel_launch(void* const* d_in, const int* in_sizes, int n_in,
                              void* d_out, int out_size, void* d_ws, size_t ws_size,
                              hipStream_t stream) {
    const float* pred   = (const float*)d_in[0];
    const float* target = (const float*)d_in[1];
    float* out = (float*)d_out;

    unsigned short* xb = (unsigned short*)d_ws;                   // 8 MB bf16
    float* fs = (float*)(xb + 2 * OFFQ);
    float* rr     = fs;                                           // 2*BN
    float* v      = rr + 2 * BN;                                  // BN
    float* scpart = v + BN;                                       // 1024
    float* parts  = scpart + 1024;                                // 512

    k_prep<<<dim3(16, 2, BATCH), 256, 0, stream>>>(pred, target, xb, rr, scpart);
    k_colsum<<<dim3(16, BATCH), 512, 0, stream>>>(xb, rr, scpart, v);
    k_loss<<<dim3(16, BATCH), 512, 0, stream>>>(xb, rr, scpart, v, parts);
    k_final<<<1, 256, 0, stream>>>(parts, out);
}

// Round 14
// 50.122 us; speedup vs baseline: 6.0629x; 1.0582x over previous
//
#include <hip/hip_runtime.h>
#include <math.h>

#define BATCH 32
#define NPTS 1024
#define DIM 64
#define EPS_DIV 1e-8f
#define EPS_NORM 1e-8f
#define BN (BATCH * NPTS)
#define OFFQ ((size_t)BATCH * NPTS * DIM)   // shorts per tensor
#define BSHORTS (NPTS * DIM)                // shorts per batch-matrix
#define BF1 ((short)0x3F80)                 // bf16(1.0)

typedef __attribute__((ext_vector_type(8))) short short8v;
typedef __attribute__((ext_vector_type(4))) float f32x4;

static __device__ __forceinline__ unsigned short f2bf(float f) {
    unsigned u = __float_as_uint(f);
    return (unsigned short)((u + 0x7FFFu + ((u >> 16) & 1u)) >> 16);
}
static __device__ __forceinline__ float bf2f(unsigned short h) {
    return __uint_as_float(((unsigned)h) << 16);
}
static __device__ __forceinline__ float fsqrt(float x) {
#if __has_builtin(__builtin_amdgcn_sqrtf)
    return __builtin_amdgcn_sqrtf(x);
#else
    return sqrtf(x);
#endif
}
// hi/lo bf16 split packed into an ext fragment (A side: [hi,lo,1,1,0..])
static __device__ __forceinline__ short8v make_extA(float v, int lk) {
    unsigned short hi = f2bf(v);
    unsigned short lo = f2bf(v - bf2f(hi));
    short8v z = (short8v){0, 0, 0, 0, 0, 0, 0, 0};
    if (lk == 0) { z[0] = (short)hi; z[1] = (short)lo; z[2] = BF1; z[3] = BF1; }
    return z;
}
// B side: [1,1,hi,lo,0..]
static __device__ __forceinline__ short8v make_extB(float v, int lk) {
    unsigned short hi = f2bf(v);
    unsigned short lo = f2bf(v - bf2f(hi));
    short8v z = (short8v){0, 0, 0, 0, 0, 0, 0, 0};
    if (lk == 0) { z[0] = BF1; z[1] = BF1; z[2] = (short)hi; z[3] = (short)lo; }
    return z;
}

// Fragment-major layout per batch-matrix: [64 rowgroups][8 cu][16 lr][8 bf16]
// shorts offset = rg*1024 + cu*128 + lr*8, cu = ks*4 + lk.
// Y is stored NEGATED so MFMA(x, -y) accumulates -x.y; with the ext MFMA
// (norms appended) acc = xs2 + yr2 - x.y = sqd / spq2 directly.

// ---- prep: 64-row chunks; cast(+negate Y) + sums + fragment-major store ----
__global__ __launch_bounds__(256) void k_prep(const float* __restrict__ p,
                                              const float* __restrict__ q,
                                              unsigned short* __restrict__ xb,
                                              float* __restrict__ rr,
                                              float* __restrict__ scpart) {
    int b = blockIdx.z, sel = blockIdx.y, chunk = blockIdx.x;
    const float* src = (sel ? q : p) + ((size_t)b * NPTS + chunk * 64) * DIM;
    unsigned short* dstb = xb + (sel ? OFFQ : 0) + (size_t)b * BSHORTS;
    float* rrb = rr + sel * BN + b * NPTS + chunk * 64;
    unsigned short sgn = sel ? 0x8000u : 0u;
    int t = threadIdx.x;
    __shared__ unsigned short lds[64][72];   // padded
    __shared__ float sm[256];
    float s = 0.f;
    #pragma unroll
    for (int it = 0; it < 4; it++) {
        int idx = it * 256 + t;              // float4 unit; 16 per row
        int row = idx >> 4, dq = idx & 15;
        float4 v = ((const float4*)src)[idx];
        s += v.x + v.y + v.z + v.w;
        unsigned short h0 = f2bf(v.x), h1 = f2bf(v.y), h2 = f2bf(v.z), h3 = f2bf(v.w);
        float r0 = bf2f(h0), r1 = bf2f(h1), r2 = bf2f(h2), r3 = bf2f(h3);
        float ss = r0 * r0 + r1 * r1 + r2 * r2 + r3 * r3;
        ushort4 o;
        o.x = h0 ^ sgn; o.y = h1 ^ sgn; o.z = h2 ^ sgn; o.w = h3 ^ sgn;
        *(ushort4*)&lds[row][dq * 4] = o;
        ss += __shfl_xor(ss, 1);
        ss += __shfl_xor(ss, 2);
        ss += __shfl_xor(ss, 4);
        ss += __shfl_xor(ss, 8);
        if ((t & 15) == 0) rrb[it * 16 + (t >> 4)] = ss;
    }
    sm[t] = s;
    __syncthreads();
    // fragment-major: 512 16-B units; unit u: rg=u>>7, cu=(u>>4)&7, lr=u&15
    #pragma unroll
    for (int o = 0; o < 2; o++) {
        int u = o * 256 + t;
        int rg = u >> 7, cu = (u >> 4) & 7, lr_ = u & 15;
        int row = rg * 16 + lr_;
        uint4 val = *(const uint4*)&lds[row][cu * 8];
        size_t dstS = (size_t)(chunk * 4 + rg) * 1024 + cu * 128 + lr_ * 8;
        *(uint4*)(dstb + dstS) = val;
    }
    for (int st = 128; st > 0; st >>= 1) {
        if (t < st) sm[t] += sm[t + st];
        __syncthreads();
    }
    if (t == 0) scpart[(sel * BATCH + b) * 16 + chunk] = sm[0];
}

// ---- pass A: block owns 64 cols x ALL rows -> v; grid (16,BATCH) x 512 ----
__global__ __launch_bounds__(512) void k_colsum(const unsigned short* __restrict__ xb,
                                                const float* __restrict__ rr,
                                                const float* __restrict__ scpart,
                                                float* __restrict__ v) {
    int b = blockIdx.y, j0 = blockIdx.x * 64;
    int t = threadIdx.x, lane = t & 63, w = t >> 6;
    int lr = lane & 15, lk = lane >> 4;
    float sps = 0.f, sqs = 0.f;
    #pragma unroll
    for (int c = 0; c < 16; c++) {
        sps += scpart[b * 16 + c];
        sqs += scpart[(BATCH + b) * 16 + c];
    }
    float sp = 1.0f / (sps + EPS_NORM), sq = 1.0f / (sqs + EPS_NORM);
    float c1 = 0.5f * sp / sq;               // xs2 = c1*rr_i
    float c2 = 0.5f * sq / sp;               // yr2 = c2*rr_j
    float csr = fsqrt(2.0f * sp * sq);       // r = csr*sqrt(acc)
    const unsigned short* xbase = xb + (size_t)b * BSHORTS;
    const unsigned short* ybase = xb + OFFQ + (size_t)b * BSHORTS;
    const float* rrp = rr + b * NPTS;
    const float* rrq = rr + BN + b * NPTS;
    // hoisted B fragments + ext (fixed cols for the whole block)
    short8v bn[2][4], bne[4];
    #pragma unroll
    for (int ks = 0; ks < 2; ks++)
        #pragma unroll
        for (int n = 0; n < 4; n++)
            bn[ks][n] = *(const short8v*)(ybase + (size_t)(blockIdx.x * 4 + n) * 1024
                                          + (ks * 4 + lk) * 128 + lr * 8);
    #pragma unroll
    for (int n = 0; n < 4; n++)
        bne[n] = make_extB(c2 * rrq[j0 + n * 16 + lr], lk);
    float csn[4] = {0.f, 0.f, 0.f, 0.f};
    #pragma unroll
    for (int it = 0; it < 2; it++) {
        int ib = w * 128 + it * 64;
        int rg0 = w * 8 + it * 4;
        f32x4 acc[4][4];
        short8v ame[4];
        #pragma unroll
        for (int m = 0; m < 4; m++) {
            ame[m] = make_extA(c1 * rrp[ib + m * 16 + lr], lk);
            #pragma unroll
            for (int n = 0; n < 4; n++) acc[m][n] = (f32x4){0.f, 0.f, 0.f, 0.f};
        }
        #pragma unroll
        for (int m = 0; m < 4; m++)
            #pragma unroll
            for (int n = 0; n < 4; n++)
                acc[m][n] = __builtin_amdgcn_mfma_f32_16x16x32_bf16(
                    ame[m], bne[n], acc[m][n], 0, 0, 0);
        #pragma unroll
        for (int ks = 0; ks < 2; ks++) {
            short8v am[4];
            #pragma unroll
            for (int m = 0; m < 4; m++)
                am[m] = *(const short8v*)(xbase + (size_t)(rg0 + m) * 1024
                                          + (ks * 4 + lk) * 128 + lr * 8);
            #pragma unroll
            for (int m = 0; m < 4; m++)
                #pragma unroll
                for (int n = 0; n < 4; n++)
                    acc[m][n] = __builtin_amdgcn_mfma_f32_16x16x32_bf16(
                        am[m], bn[ks][n], acc[m][n], 0, 0, 0);
        }
        #pragma unroll
        for (int m = 0; m < 4; m++)
            #pragma unroll
            for (int n = 0; n < 4; n++)
                #pragma unroll
                for (int r = 0; r < 4; r++)
                    csn[n] += fsqrt(fmaxf(acc[m][n][r], 0.f));
    }
    #pragma unroll
    for (int n = 0; n < 4; n++) {
        csn[n] += __shfl_xor(csn[n], 16);
        csn[n] += __shfl_xor(csn[n], 32);
    }
    __shared__ float cs[8][64];
    if (lk == 0) {
        #pragma unroll
        for (int n = 0; n < 4; n++) cs[w][n * 16 + lr] = csn[n];
    }
    __syncthreads();
    if (t < 64) {
        float s = 0.f;
        #pragma unroll
        for (int ww = 0; ww < 8; ww++) s += cs[ww][t];
        float fac = csr * (10.0f / NPTS);
        v[b * NPTS + j0 + t] = 1.0f / (1.0f - s * fac + EPS_DIV);
    }
}

// ---- pass B: block owns 64 rows x ALL cols -> loss partial; grid (16,BATCH) x 512 ----
__global__ __launch_bounds__(512) void k_loss(const unsigned short* __restrict__ xb,
                                              const float* __restrict__ rr,
                                              const float* __restrict__ scpart,
                                              const float* __restrict__ v,
                                              float* __restrict__ parts) {
    int b = blockIdx.y, i0 = blockIdx.x * 64;
    int t = threadIdx.x, lane = t & 63, w = t >> 6;
    int lr = lane & 15, lk = lane >> 4;
    __shared__ float svs[NPTS];
    __shared__ float red[256];
    __shared__ float a1s[8][64], a2s[8][64];
    if (t < 256) ((float4*)svs)[t] = ((const float4*)(v + (size_t)b * NPTS))[t];
    float sps = 0.f, sqs = 0.f;
    #pragma unroll
    for (int c = 0; c < 16; c++) {
        sps += scpart[b * 16 + c];
        sqs += scpart[(BATCH + b) * 16 + c];
    }
    float sp = 1.0f / (sps + EPS_NORM), sq = 1.0f / (sqs + EPS_NORM);
    float c1 = 0.5f * sp / sq;
    float c2 = 0.5f * sq / sp;
    float csr = fsqrt(2.0f * sp * sq);
    float t10 = 10.0f * csr;
    __syncthreads();
    if (t < 256) red[t] = svs[t] + svs[t + 256] + svs[t + 512] + svs[t + 768];
    __syncthreads();
    for (int st = 128; st > 0; st >>= 1) {
        if (t < st && t < 256) red[t] += red[t + st];
        __syncthreads();
    }
    float sV = red[0];
    const unsigned short* xbase = xb + (size_t)b * BSHORTS;
    const unsigned short* ybase = xb + OFFQ + (size_t)b * BSHORTS;
    const float* rrq = rr + BN + b * NPTS;
    // hoisted A fragments + ext (fixed rows for the whole block)
    short8v am[2][4], ame[4];
    #pragma unroll
    for (int ks = 0; ks < 2; ks++)
        #pragma unroll
        for (int m = 0; m < 4; m++)
            am[ks][m] = *(const short8v*)(xbase + (size_t)(blockIdx.x * 4 + m) * 1024
                                          + (ks * 4 + lk) * 128 + lr * 8);
    #pragma unroll
    for (int m = 0; m < 4; m++)
        ame[m] = make_extA(c1 * rr[b * NPTS + i0 + m * 16 + lr], lk);
    float a1[4][4] = {}, a2[4][4] = {};
    #pragma unroll
    for (int it = 0; it < 2; it++) {
        int jb = w * 128 + it * 64;
        int rg0 = w * 8 + it * 4;
        f32x4 acc[4][4];
        short8v bne[4];
        float cvj[4];
        #pragma unroll
        for (int n = 0; n < 4; n++) {
            int col = jb + n * 16 + lr;
            bne[n] = make_extB(c2 * rrq[col], lk);
            cvj[n] = csr * svs[col];
            #pragma unroll
            for (int m = 0; m < 4; m++) acc[m][n] = (f32x4){0.f, 0.f, 0.f, 0.f};
        }
        #pragma unroll
        for (int m = 0; m < 4; m++)
            #pragma unroll
            for (int n = 0; n < 4; n++)
                acc[m][n] = __builtin_amdgcn_mfma_f32_16x16x32_bf16(
                    ame[m], bne[n], acc[m][n], 0, 0, 0);
        #pragma unroll
        for (int ks = 0; ks < 2; ks++) {
            short8v bnf[4];
            #pragma unroll
            for (int n = 0; n < 4; n++)
                bnf[n] = *(const short8v*)(ybase + (size_t)(rg0 + n) * 1024
                                           + (ks * 4 + lk) * 128 + lr * 8);
            #pragma unroll
            for (int m = 0; m < 4; m++)
                #pragma unroll
                for (int n = 0; n < 4; n++)
                    acc[m][n] = __builtin_amdgcn_mfma_f32_16x16x32_bf16(
                        am[ks][m], bnf[n], acc[m][n], 0, 0, 0);
        }
        #pragma unroll
        for (int n = 0; n < 4; n++) {
            #pragma unroll
            for (int m = 0; m < 4; m++)
                #pragma unroll
                for (int r = 0; r < 4; r++) {
                    float rt = fsqrt(fmaxf(acc[m][n][r], 0.f));
                    float tv = cvj[n] * rt;           // = r_ij * v_j
                    a1[m][r] += tv;
                    a2[m][r] = fmaf(tv, fmaf(-t10, rt, 1.0f), a2[m][r]);
                }
        }
    }
    #pragma unroll
    for (int m = 0; m < 4; m++)
        #pragma unroll
        for (int r = 0; r < 4; r++) {
            #pragma unroll
            for (int st = 1; st < 16; st <<= 1) {
                a1[m][r] += __shfl_xor(a1[m][r], st);
                a2[m][r] += __shfl_xor(a2[m][r], st);
            }
        }
    if (lr == 0) {
        #pragma unroll
        for (int m = 0; m < 4; m++)
            #pragma unroll
            for (int r = 0; r < 4; r++) {
                a1s[w][m * 16 + lk * 4 + r] = a1[m][r];
                a2s[w][m * 16 + lk * 4 + r] = a2[m][r];
            }
    }
    __syncthreads();
    if (t < 64) {
        float A1 = 0.f, A2 = 0.f;
        #pragma unroll
        for (int ww = 0; ww < 8; ww++) {
            A1 += a1s[ww][t];
            A2 += a2s[ww][t];
        }
        float u = 1.0f / (sV - 10.0f * A1 + EPS_DIV);
        float lp = u * A2;
        #pragma unroll
        for (int st = 1; st < 64; st <<= 1) lp += __shfl_xor(lp, st);
        if (t == 0) parts[b * 16 + blockIdx.x] = lp;
    }
}

// ---- final: one block reduces 512 partials ----
__global__ void k_final(const float* __restrict__ parts, float* __restrict__ out) {
    __shared__ float sm[256];
    int t = threadIdx.x;
    float a = parts[t] + parts[t + 256];
    sm[t] = a;
    __syncthreads();
    for (int st = 128; st > 0; st >>= 1) {
        if (t < st) sm[t] += sm[t + st];
        __syncthreads();
    }
    if (t == 0) out[0] = sm[0] / (float)BATCH;
}

extern "C" void kernel_launch(void* const* d_in, const int* in_sizes, int n_in,
                              void* d_out, int out_size, void* d_ws, size_t ws_size,
                              hipStream_t stream) {
    const float* pred   = (const float*)d_in[0];
    const float* target = (const float*)d_in[1];
    float* out = (float*)d_out;

    unsigned short* xb = (unsigned short*)d_ws;                   // 8 MB bf16
    float* fs = (float*)(xb + 2 * OFFQ);
    float* rr     = fs;                                           // 2*BN
    float* v      = rr + 2 * BN;                                  // BN
    float* scpart = v + BN;                                       // 1024
    float* parts  = scpart + 1024;                                // 512

    k_prep<<<dim3(16, 2, BATCH), 256, 0, stream>>>(pred, target, xb, rr, scpart);
    k_colsum<<<dim3(16, BATCH), 512, 0, stream>>>(xb, rr, scpart, v);
    k_loss<<<dim3(16, BATCH), 512, 0, stream>>>(xb, rr, scpart, v, parts);
    k_final<<<1, 256, 0, stream>>>(parts, out);
}

// Round 15
// 45.168 us; speedup vs baseline: 6.7277x; 1.1097x over previous
//
#include <hip/hip_runtime.h>
#include <math.h>

#define BATCH 32
#define NPTS 1024
#define DIM 64
#define EPS_DIV 1e-8f
#define EPS_NORM 1e-8f
#define BN (BATCH * NPTS)
#define OFFQ ((size_t)BATCH * NPTS * DIM)   // shorts per tensor
#define BSHORTS (NPTS * DIM)                // shorts per batch-matrix
#define BF1 ((short)0x3F80)                 // bf16(1.0)

typedef __attribute__((ext_vector_type(8))) short short8v;
typedef __attribute__((ext_vector_type(4))) float f32x4;

static __device__ __forceinline__ unsigned short f2bf(float f) {
    unsigned u = __float_as_uint(f);
    return (unsigned short)((u + 0x7FFFu + ((u >> 16) & 1u)) >> 16);
}
static __device__ __forceinline__ float bf2f(unsigned short h) {
    return __uint_as_float(((unsigned)h) << 16);
}
static __device__ __forceinline__ float fsqrt(float x) {
#if __has_builtin(__builtin_amdgcn_sqrtf)
    return __builtin_amdgcn_sqrtf(x);
#else
    return sqrtf(x);
#endif
}
// hi/lo bf16 split fragments for the append-K norm trick
static __device__ __forceinline__ short8v make_extA(float v, int lk) {
    unsigned short hi = f2bf(v);
    unsigned short lo = f2bf(v - bf2f(hi));
    short8v z = (short8v){0, 0, 0, 0, 0, 0, 0, 0};
    if (lk == 0) { z[0] = (short)hi; z[1] = (short)lo; z[2] = BF1; z[3] = BF1; }
    return z;
}
static __device__ __forceinline__ short8v make_extB(float v, int lk) {
    unsigned short hi = f2bf(v);
    unsigned short lo = f2bf(v - bf2f(hi));
    short8v z = (short8v){0, 0, 0, 0, 0, 0, 0, 0};
    if (lk == 0) { z[0] = BF1; z[1] = BF1; z[2] = (short)hi; z[3] = (short)lo; }
    return z;
}

// Fragment-major layout per batch-matrix: [64 rowgroups][8 cu][16 lr][8 bf16]
// shorts offset = rg*1024 + cu*128 + lr*8; dims covered by cu are cu*8..cu*8+7.
// Y stored NEGATED; with append-K MFMA: acc = sqd / (2 sp sq) directly.

// ---- prep: cast(+neg Y) + sums + row sumsq + Y column-sum partials ----
__global__ __launch_bounds__(256) void k_prep(const float* __restrict__ p,
                                              const float* __restrict__ q,
                                              unsigned short* __restrict__ xb,
                                              float* __restrict__ rr,
                                              float* __restrict__ scpart,
                                              float* __restrict__ Sypart) {
    int b = blockIdx.z, sel = blockIdx.y, chunk = blockIdx.x;
    const float* src = (sel ? q : p) + ((size_t)b * NPTS + chunk * 64) * DIM;
    unsigned short* dstb = xb + (sel ? OFFQ : 0) + (size_t)b * BSHORTS;
    float* rrb = rr + sel * BN + b * NPTS + chunk * 64;
    unsigned short sgn = sel ? 0x8000u : 0u;
    int t = threadIdx.x;
    __shared__ unsigned short lds[64][72];   // padded
    __shared__ float sm[256];
    __shared__ float syred[4][64];
    float s = 0.f;
    #pragma unroll
    for (int it = 0; it < 4; it++) {
        int idx = it * 256 + t;              // float4 unit; 16 per row
        int row = idx >> 4, dq = idx & 15;
        float4 v = ((const float4*)src)[idx];
        s += v.x + v.y + v.z + v.w;
        unsigned short h0 = f2bf(v.x), h1 = f2bf(v.y), h2 = f2bf(v.z), h3 = f2bf(v.w);
        float r0 = bf2f(h0), r1 = bf2f(h1), r2 = bf2f(h2), r3 = bf2f(h3);
        float ss = r0 * r0 + r1 * r1 + r2 * r2 + r3 * r3;
        ushort4 o;
        o.x = h0 ^ sgn; o.y = h1 ^ sgn; o.z = h2 ^ sgn; o.w = h3 ^ sgn;
        *(ushort4*)&lds[row][dq * 4] = o;
        ss += __shfl_xor(ss, 1);
        ss += __shfl_xor(ss, 2);
        ss += __shfl_xor(ss, 4);
        ss += __shfl_xor(ss, 8);
        if ((t & 15) == 0) rrb[it * 16 + (t >> 4)] = ss;
    }
    sm[t] = s;
    __syncthreads();
    // fragment-major store
    #pragma unroll
    for (int o = 0; o < 2; o++) {
        int u = o * 256 + t;
        int rg = u >> 7, cu = (u >> 4) & 7, lr_ = u & 15;
        int row = rg * 16 + lr_;
        uint4 val = *(const uint4*)&lds[row][cu * 8];
        size_t dstS = (size_t)(chunk * 4 + rg) * 1024 + cu * 128 + lr_ * 8;
        *(uint4*)(dstb + dstS) = val;
    }
    // Y column-sum partials (stored values, i.e. negated for sel=1)
    {
        int d = t & 63, qd = t >> 6;
        float sy = 0.f;
        #pragma unroll
        for (int rw = 0; rw < 16; rw++) sy += bf2f(lds[qd * 16 + rw][d]);
        syred[qd][d] = sy;
    }
    __syncthreads();
    if (t < 64 && sel)
        Sypart[((size_t)b * 16 + chunk) * 64 + t] =
            syred[0][t] + syred[1][t] + syred[2][t] + syred[3][t];
    for (int st = 128; st > 0; st >>= 1) {
        if (t < st) sm[t] += sm[t + st];
        __syncthreads();
    }
    if (t == 0) scpart[(sel * BATCH + b) * 16 + chunk] = sm[0];
}

// ---- the single GEMM pass: colsums -> v directly, plain rowsum partials ----
__global__ __launch_bounds__(512) void k_main(const unsigned short* __restrict__ xb,
                                              const float* __restrict__ rr,
                                              const float* __restrict__ scpart,
                                              float* __restrict__ v,
                                              float* __restrict__ Rpart) {
    int b = blockIdx.y, jc = blockIdx.x;
    int j0 = jc * 64;
    int t = threadIdx.x, lane = t & 63, w = t >> 6;
    int lr = lane & 15, lk = lane >> 4;
    float sps = 0.f, sqs = 0.f;
    #pragma unroll
    for (int c = 0; c < 16; c++) {
        sps += scpart[b * 16 + c];
        sqs += scpart[(BATCH + b) * 16 + c];
    }
    float sp = 1.0f / (sps + EPS_NORM), sq = 1.0f / (sqs + EPS_NORM);
    float c1 = 0.5f * sp / sq;               // xs2 = c1*rr_i
    float c2 = 0.5f * sq / sp;               // yr2 = c2*rr_j
    float csr = fsqrt(2.0f * sp * sq);       // r = csr*sqrt(acc)
    const unsigned short* xbase = xb + (size_t)b * BSHORTS;
    const unsigned short* ybase = xb + OFFQ + (size_t)b * BSHORTS;
    const float* rrp = rr + b * NPTS;
    const float* rrq = rr + BN + b * NPTS;
    short8v bn[2][4], bne[4];
    #pragma unroll
    for (int ks = 0; ks < 2; ks++)
        #pragma unroll
        for (int n = 0; n < 4; n++)
            bn[ks][n] = *(const short8v*)(ybase + (size_t)(jc * 4 + n) * 1024
                                          + (ks * 4 + lk) * 128 + lr * 8);
    #pragma unroll
    for (int n = 0; n < 4; n++)
        bne[n] = make_extB(c2 * rrq[j0 + n * 16 + lr], lk);
    float csn[4] = {0.f, 0.f, 0.f, 0.f};
    #pragma unroll
    for (int it = 0; it < 2; it++) {
        int ib = w * 128 + it * 64;
        int rg0 = w * 8 + it * 4;
        f32x4 acc[4][4];
        short8v ame[4];
        #pragma unroll
        for (int m = 0; m < 4; m++) {
            ame[m] = make_extA(c1 * rrp[ib + m * 16 + lr], lk);
            #pragma unroll
            for (int n = 0; n < 4; n++) acc[m][n] = (f32x4){0.f, 0.f, 0.f, 0.f};
        }
        #pragma unroll
        for (int m = 0; m < 4; m++)
            #pragma unroll
            for (int n = 0; n < 4; n++)
                acc[m][n] = __builtin_amdgcn_mfma_f32_16x16x32_bf16(
                    ame[m], bne[n], acc[m][n], 0, 0, 0);
        #pragma unroll
        for (int ks = 0; ks < 2; ks++) {
            short8v am[4];
            #pragma unroll
            for (int m = 0; m < 4; m++)
                am[m] = *(const short8v*)(xbase + (size_t)(rg0 + m) * 1024
                                          + (ks * 4 + lk) * 128 + lr * 8);
            #pragma unroll
            for (int m = 0; m < 4; m++)
                #pragma unroll
                for (int n = 0; n < 4; n++)
                    acc[m][n] = __builtin_amdgcn_mfma_f32_16x16x32_bf16(
                        am[m], bn[ks][n], acc[m][n], 0, 0, 0);
        }
        float rsum[4][4];
        #pragma unroll
        for (int m = 0; m < 4; m++)
            #pragma unroll
            for (int r = 0; r < 4; r++) rsum[m][r] = 0.f;
        #pragma unroll
        for (int m = 0; m < 4; m++)
            #pragma unroll
            for (int n = 0; n < 4; n++)
                #pragma unroll
                for (int r = 0; r < 4; r++) {
                    float rt = fsqrt(fmaxf(acc[m][n][r], 0.f));
                    csn[n] += rt;
                    rsum[m][r] += rt;
                }
        // reduce rowsums over the 16 lr lanes, write partials
        #pragma unroll
        for (int m = 0; m < 4; m++)
            #pragma unroll
            for (int r = 0; r < 4; r++) {
                #pragma unroll
                for (int st = 1; st < 16; st <<= 1)
                    rsum[m][r] += __shfl_xor(rsum[m][r], st);
            }
        if (lr == 0) {
            #pragma unroll
            for (int m = 0; m < 4; m++)
                #pragma unroll
                for (int r = 0; r < 4; r++)
                    Rpart[((size_t)b * NPTS + ib + m * 16 + lk * 4 + r) * 16 + jc]
                        = rsum[m][r];
        }
    }
    #pragma unroll
    for (int n = 0; n < 4; n++) {
        csn[n] += __shfl_xor(csn[n], 16);
        csn[n] += __shfl_xor(csn[n], 32);
    }
    __shared__ float cs[8][64];
    if (lk == 0) {
        #pragma unroll
        for (int n = 0; n < 4; n++) cs[w][n * 16 + lr] = csn[n];
    }
    __syncthreads();
    if (t < 64) {
        float s = 0.f;
        #pragma unroll
        for (int ww = 0; ww < 8; ww++) s += cs[ww][t];
        float fac = csr * (10.0f / NPTS);
        v[b * NPTS + j0 + t] = 1.0f / (1.0f - s * fac + EPS_DIV);
    }
}

// ---- mid: per batch, mean-field a1 + closed-form q -> per-batch loss ----
__global__ __launch_bounds__(256) void k_mid(const unsigned short* __restrict__ xb,
                                             const float* __restrict__ rr,
                                             const float* __restrict__ scpart,
                                             const float* __restrict__ v,
                                             const float* __restrict__ Rpart,
                                             const float* __restrict__ Sypart,
                                             float* __restrict__ lossb) {
    int b = blockIdx.x, t = threadIdx.x;
    __shared__ float Syn[64];
    __shared__ float red[256];
    float sps = 0.f, sqs = 0.f;
    #pragma unroll
    for (int c = 0; c < 16; c++) {
        sps += scpart[b * 16 + c];
        sqs += scpart[(BATCH + b) * 16 + c];
    }
    float sp = 1.0f / (sps + EPS_NORM), sq = 1.0f / (sqs + EPS_NORM);
    float sp2 = sp * sp, sq2 = sq * sq, spq = sp * sq;
    float csr = fsqrt(2.0f * spq);
    if (t < 64) {
        float s = 0.f;
        #pragma unroll
        for (int c = 0; c < 16; c++) s += Sypart[((size_t)b * 16 + c) * 64 + t];
        Syn[t] = s;                           // = -sum_j yhat_j[dim t]
    }
    float4 vv = ((const float4*)(v + (size_t)b * NPTS))[t];
    float pv = vv.x + vv.y + vv.z + vv.w;
    float4 rq = ((const float4*)(rr + BN + (size_t)b * NPTS))[t];
    float pr = rq.x + rq.y + rq.z + rq.w;
    red[t] = pv;
    __syncthreads();
    for (int st = 128; st > 0; st >>= 1) {
        if (t < st) red[t] += red[t + st];
        __syncthreads();
    }
    float sV = red[0];
    __syncthreads();
    red[t] = pr;
    __syncthreads();
    for (int st = 128; st > 0; st >>= 1) {
        if (t < st) red[t] += red[t + st];
        __syncthreads();
    }
    float RRQ = red[0];
    __syncthreads();
    float seps = sV - (float)NPTS;
    float a1fac = csr * (1.0f + seps * (1.0f / NPTS));
    float lp = 0.f;
    #pragma unroll
    for (int k = 0; k < 4; k++) {
        int row = k * 256 + t;
        const float* rp = Rpart + ((size_t)b * NPTS + row) * 16;
        float R = 0.f;
        #pragma unroll
        for (int c = 0; c < 16; c++) R += rp[c];
        const unsigned short* xr = xb + (size_t)b * BSHORTS
                                      + (size_t)(row >> 4) * 1024 + (row & 15) * 8;
        float dot = 0.f;
        #pragma unroll
        for (int cu = 0; cu < 8; cu++) {
            uint4 u4 = *(const uint4*)(xr + cu * 128);
            const unsigned short* us = (const unsigned short*)&u4;
            #pragma unroll
            for (int e = 0; e < 8; e++)
                dot += bf2f(us[e]) * Syn[cu * 8 + e];
        }
        float a1 = a1fac * R;                 // mean-field v correction
        float qq = (float)NPTS * sp2 * rr[b * NPTS + row] + sq2 * RRQ
                   + 2.0f * spq * dot;        // sum_j sqd_ij (v ~ 1)
        float u = 1.0f / (sV - 10.0f * a1 + EPS_DIV);
        lp += u * (a1 - 10.0f * qq);
    }
    red[t] = lp;
    __syncthreads();
    for (int st = 128; st > 0; st >>= 1) {
        if (t < st) red[t] += red[t + st];
        __syncthreads();
    }
    if (t == 0) lossb[b] = red[0];
}

// ---- final: sum 32 batch losses ----
__global__ void k_final(const float* __restrict__ lossb, float* __restrict__ out) {
    int t = threadIdx.x;
    float a = (t < BATCH) ? lossb[t] : 0.f;
    #pragma unroll
    for (int st = 1; st < 64; st <<= 1) a += __shfl_xor(a, st);
    if (t == 0) out[0] = a / (float)BATCH;
}

extern "C" void kernel_launch(void* const* d_in, const int* in_sizes, int n_in,
                              void* d_out, int out_size, void* d_ws, size_t ws_size,
                              hipStream_t stream) {
    const float* pred   = (const float*)d_in[0];
    const float* target = (const float*)d_in[1];
    float* out = (float*)d_out;

    unsigned short* xb = (unsigned short*)d_ws;                   // 8 MB bf16
    float* fs = (float*)(xb + 2 * OFFQ);
    float* rr     = fs;                                           // 2*BN
    float* v      = rr + 2 * BN;                                  // BN
    float* scpart = v + BN;                                       // 1024
    float* Sypart = scpart + 1024;                                // 32*16*64
    float* Rpart  = Sypart + BATCH * 16 * 64;                     // BN*16
    float* lossb  = Rpart + (size_t)BN * 16;                      // 32

    k_prep<<<dim3(16, 2, BATCH), 256, 0, stream>>>(pred, target, xb, rr, scpart, Sypart);
    k_main<<<dim3(16, BATCH), 512, 0, stream>>>(xb, rr, scpart, v, Rpart);
    k_mid<<<BATCH, 256, 0, stream>>>(xb, rr, scpart, v, Rpart, Sypart, lossb);
    k_final<<<1, 64, 0, stream>>>(lossb, out);
}